// Round 6
// baseline (306.488 us; speedup 1.0000x reference)
//
#include <hip/hip_runtime.h>
#include <hip/hip_bf16.h>

#define NB 8
#define NC 256
#define NCI 128
#define NPOS 6272   // 8*28*28
#define NM 1568     // 8*14*14
#define PTOT 50176  // 8*6272

typedef __attribute__((ext_vector_type(8))) short bf16x8;
typedef __attribute__((ext_vector_type(4))) float f32x4;
#define MFMA(a,b,c) __builtin_amdgcn_mfma_f32_16x16x32_bf16((a),(b),(c),0,0,0)

__device__ __forceinline__ short f2bf(float f){
  union{float f; unsigned u;} v; v.f=f;
  unsigned r=(v.u + 0x7FFFu + ((v.u>>16)&1u))>>16;
  return (short)r;
}
__device__ __forceinline__ float bf2f(short s){
  union{unsigned u; float f;} v; v.u=((unsigned)(unsigned short)s)<<16; return v.f;
}
__device__ __forceinline__ unsigned pack2(float lo, float hi){
  return (unsigned)(unsigned short)f2bf(lo) | ((unsigned)(unsigned short)f2bf(hi) << 16);
}

// ---------------- weights fp32 -> bf16 (Ww gets hi/lo split) ----------------
__global__ void k_cvt_w(const float* __restrict__ Wt, const float* __restrict__ Wp,
                        const float* __restrict__ Wg, const float* __restrict__ Ww,
                        short* __restrict__ out){
  int i = blockIdx.x*256 + threadIdx.x;   // 131072 total
  if (i < 98304){
    const float* src; int off;
    if (i < 32768)      { src = Wt; off = i; }
    else if (i < 65536) { src = Wp; off = i-32768; }
    else                { src = Wg; off = i-65536; }
    out[i] = f2bf(src[off]);
  } else {
    float v = Ww[i-98304];
    short hi = f2bf(v);
    out[i] = hi;                                  // Ww_hi at [98304,131072)
    out[i+32768] = f2bf(v - bf2f(hi));            // Ww_lo at [131072,163840)
  }
}

// ---------------- x (c,pos) fp32 -> xT (pos,c) bf16 (vectorized b128 stores) ----------------
__global__ void k_transpose(const float* __restrict__ x, short* __restrict__ xT){
  __shared__ float tile[64][33];
  int b = blockIdx.z, c0 = blockIdx.y*64, p0 = blockIdx.x*32;
  int tx = threadIdx.x & 31, ty = threadIdx.x >> 5;   // ty in [0,8)
  const float* xb = x + (size_t)b*NC*NPOS;
  #pragma unroll
  for (int k=0;k<8;k++)
    tile[ty+8*k][tx] = xb[(size_t)(c0+ty+8*k)*NPOS + p0 + tx];
  __syncthreads();
  short* xTb = xT + (size_t)b*NPOS*NC;
  int pos = threadIdx.x >> 3, cg = threadIdx.x & 7;
  bf16x8 v;
  #pragma unroll
  for (int i=0;i<8;i++) v[i] = f2bf(tile[cg*8+i][pos]);
  *(bf16x8*)&xTb[(size_t)(p0+pos)*NC + c0 + cg*8] = v;
}

// ---------------- 3 projection convs fused: one pass over xT, widx loop inside ----------------
__global__ __launch_bounds__(256) void k_conv(const short* __restrict__ xT, const short* __restrict__ Wbf,
                        const float* __restrict__ bt, const float* __restrict__ bp, const float* __restrict__ bg,
                        short* __restrict__ theta, short* __restrict__ phiF, short* __restrict__ gF){
  int b = blockIdx.z;
  int wv = threadIdx.x >> 6, lane = threadIdx.x & 63;
  int l16 = lane & 15, lg = lane >> 4;
  int p0 = blockIdx.x*128 + wv*32;
  int c0 = blockIdx.y*64;
  const short* xTb = xT + (size_t)b*NPOS*NC;
  bf16x8 a[2][8];
  #pragma unroll
  for (int ps=0;ps<2;ps++)
    #pragma unroll
    for (int ks=0;ks<8;ks++)
      a[ps][ks] = *(const bf16x8*)&xTb[(size_t)(p0+ps*16+l16)*NC + ks*32 + lg*8];
  for (int widx=0; widx<3; widx++){
    const short* Wb = Wbf + widx*32768;
    const float* bias = (widx==0) ? bt : ((widx==1) ? bp : bg);
    short* outp = (widx==0) ? theta : ((widx==1) ? phiF : gF);
    float bv[4];
    #pragma unroll
    for (int cs=0;cs<4;cs++) bv[cs] = bias[c0+cs*16+l16];
    f32x4 acc[2][4] = {};
    #pragma unroll
    for (int ks=0;ks<8;ks++)
      #pragma unroll
      for (int cs=0;cs<4;cs++){
        bf16x8 wf = *(const bf16x8*)&Wb[(c0+cs*16+l16)*NC + ks*32 + lg*8];
        acc[0][cs] = MFMA(a[0][ks], wf, acc[0][cs]);
        acc[1][cs] = MFMA(a[1][ks], wf, acc[1][cs]);
      }
    short* ob = outp + (size_t)b*NPOS*NCI;
    #pragma unroll
    for (int ps=0;ps<2;ps++)
      #pragma unroll
      for (int cs=0;cs<4;cs++)
        #pragma unroll
        for (int j=0;j<4;j++){
          int pos = p0 + ps*16 + lg*4 + j;
          int co  = c0 + cs*16 + l16;
          ob[(size_t)pos*NCI + co] = f2bf(acc[ps][cs][j] + bv[cs]);
        }
  }
}

// ---------------- (1,2,2) max-pool: phiF(pos,128)->phiP(M,128); gF(pos,128)->gP(128,M) ----------------
__global__ void k_pool(const short* __restrict__ phiF, const short* __restrict__ gF,
                       short* __restrict__ phiP, short* __restrict__ gP){
  __shared__ short gb[128][17];
  int b = blockIdx.y, m0 = blockIdx.x*16;
  int lm = threadIdx.x >> 4, cg = threadIdx.x & 15, ci0 = cg*8;
  int m = m0 + lm;
  int tt = m/196, r = m%196, h2 = r/14, w2 = r%14;
  int pbase = tt*784 + h2*56 + w2*2;
  const short* pF  = phiF + (size_t)b*NPOS*NCI;
  const short* gFb = gF   + (size_t)b*NPOS*NCI;
  float pb[8], gv[8];
  #pragma unroll
  for (int i=0;i<8;i++){ pb[i]=-1e30f; gv[i]=-1e30f; }
  #pragma unroll
  for (int dh=0;dh<2;dh++)
    #pragma unroll
    for (int dw=0;dw<2;dw++){
      int pos = pbase + dh*28 + dw;
      bf16x8 v = *(const bf16x8*)&pF[(size_t)pos*NCI+ci0];
      bf16x8 g = *(const bf16x8*)&gFb[(size_t)pos*NCI+ci0];
      #pragma unroll
      for (int i=0;i<8;i++){ pb[i]=fmaxf(pb[i],bf2f(v[i])); gv[i]=fmaxf(gv[i],bf2f(g[i])); }
    }
  bf16x8 po;
  #pragma unroll
  for (int i=0;i<8;i++) po[i]=f2bf(pb[i]);
  *(bf16x8*)&phiP[(size_t)b*NM*NCI + (size_t)m*NCI + ci0] = po;
  #pragma unroll
  for (int i=0;i<8;i++) gb[ci0+i][lm] = f2bf(gv[i]);
  __syncthreads();
  if (threadIdx.x < 128){
    int row = threadIdx.x;
    bf16x8 a, c;
    #pragma unroll
    for (int j=0;j<8;j++){ a[j]=gb[row][j]; c[j]=gb[row][8+j]; }
    short* dst = gP + (size_t)b*NCI*NM + (size_t)row*NM + m0;
    *(bf16x8*)&dst[0] = a;
    *(bf16x8*)&dst[8] = c;
  }
}

// ---------------- flash attention v5: 2 waves x 32 q, swapped QK, in-lane-group P redistribution ----------------
__global__ __launch_bounds__(128,2) void k_attn(const short* __restrict__ theta, const short* __restrict__ phiP,
                       const short* __restrict__ gP, short* __restrict__ yhi, short* __restrict__ ylo){
  __shared__ __align__(16) char tiles[2][16384];        // [buf][ phi 8KB | g 8KB ]
  __shared__ __align__(16) unsigned pbs[2][2][320];     // [wave][qi][16 rows x 20 dw]
  int t = threadIdx.x;
  int wv = t >> 6, lane = t & 63;
  int l16 = lane & 15, lg = lane >> 4;
  int b = blockIdx.x & 7, qt = blockIdx.x >> 3;         // batch on low bits -> XCD-local K/V
  int q0 = qt*64 + wv*32;
  const short* th = theta + (size_t)b*NPOS*NCI;
  const char* gph = (const char*)(phiP + (size_t)b*NM*NCI);
  const char* gpg = (const char*)(gP   + (size_t)b*NCI*NM);

  // ---- staging geometry: 128 threads stage 16 KB (8 x 16B chunks each) ----
  int pr = (t >> 4) & 7, ps = t & 15;                   // phi rows pr+8k, slot ps
  int gr = t >> 2, gs = t & 3;                          // g rows gr+32k, chunk gs
  int lw_p[4], lw_g[4]; size_t go_p[4], go_g[4];
  #pragma unroll
  for (int k=0;k<4;k++){
    lw_p[k] = (pr+8*k)*256 + ((ps ^ pr) << 4);
    go_p[k] = (size_t)(pr+8*k)*256 + ps*16;
    lw_g[k] = 8192 + (gr+32*k)*64 + ((gs ^ (gr & 3)) << 4);
    go_g[k] = (size_t)(gr+32*k)*(NM*2) + gs*16;
  }
  // ---- fragment read offsets (swizzled) ----
  int rp[2][4];
  #pragma unroll
  for (int mi=0;mi<2;mi++)
    #pragma unroll
    for (int kc=0;kc<4;kc++)
      rp[mi][kc] = (mi*16+l16)*256 + (((kc*4+lg) ^ (l16 & 7)) << 4);
  int rg[8];
  #pragma unroll
  for (int ct=0;ct<8;ct++)
    rg[ct] = 8192 + (ct*16+l16)*64 + ((lg ^ (l16 & 3)) << 4);

  // ---- P redistribution constants ----
  int lgs01 = (2*lg) & 3, lgs23 = (2*lg+1) & 3;
  int mi2 = (lg >> 1) * 2;
  int rbase = l16*20;

  // ---- Q fragments (B-operand of swapped QK): rows q0+qi*16+l16 ----
  bf16x8 qf[2][4];
  #pragma unroll
  for (int qi=0;qi<2;qi++)
    #pragma unroll
    for (int kc=0;kc<4;kc++)
      qf[qi][kc] = *(const bf16x8*)&th[(size_t)(q0+qi*16+l16)*NCI + kc*32 + lg*8];
  f32x4 acc[2][8] = {};
  float lsum[2] = {0.f, 0.f};

  // ---- prologue: stage tile 0 ----
  {
    uint4 A[8];
    #pragma unroll
    for (int k=0;k<4;k++){ A[k] = *(const uint4*)(gph + go_p[k]); A[4+k] = *(const uint4*)(gpg + go_g[k]); }
    #pragma unroll
    for (int k=0;k<4;k++){ *(uint4*)(tiles[0] + lw_p[k]) = A[k]; *(uint4*)(tiles[0] + lw_g[k]) = A[4+k]; }
  }
  __syncthreads();

  int cur = 0;
  for (int ms=0; ms<49; ms++){
    uint4 A[8];
    if (ms < 48){
      size_t pb_ = (size_t)(ms+1)*8192;
      size_t gb_ = (size_t)(ms+1)*64;
      #pragma unroll
      for (int k=0;k<4;k++){ A[k] = *(const uint4*)(gph + pb_ + go_p[k]); A[4+k] = *(const uint4*)(gpg + gb_ + go_g[k]); }
    }
    const char* L = tiles[cur];
    bf16x8 pf[2][4];
    #pragma unroll
    for (int mi=0;mi<2;mi++)
      #pragma unroll
      for (int kc=0;kc<4;kc++)
        pf[mi][kc] = *(const bf16x8*)(L + rp[mi][kc]);
    // swapped QK: S(row=m, col=q): s[qi][mi]
    f32x4 s[2][2] = {};
    __builtin_amdgcn_s_setprio(1);
    #pragma unroll
    for (int qi=0;qi<2;qi++)
      #pragma unroll
      for (int mi=0;mi<2;mi++)
        #pragma unroll
        for (int kc=0;kc<4;kc++)
          s[qi][mi] = MFMA(pf[mi][kc], qf[qi][kc], s[qi][mi]);
    __builtin_amdgcn_s_setprio(0);
    bf16x8 gf[8];
    #pragma unroll
    for (int ct=0;ct<8;ct++)
      gf[ct] = *(const bf16x8*)(L + rg[ct]);
    // exp + pack pairs + in-wave redistribution via tiny LDS (no barrier: per-wave region)
    #pragma unroll
    for (int qi=0;qi<2;qi++){
      float e0=__expf(s[qi][0][0]), e1=__expf(s[qi][0][1]), e2=__expf(s[qi][0][2]), e3=__expf(s[qi][0][3]);
      float e4=__expf(s[qi][1][0]), e5=__expf(s[qi][1][1]), e6=__expf(s[qi][1][2]), e7=__expf(s[qi][1][3]);
      lsum[qi] += (e0+e1)+(e2+e3)+(e4+e5)+(e6+e7);
      uint4 pk;
      pk.x = pack2(e0,e1); pk.y = pack2(e2,e3); pk.z = pack2(e4,e5); pk.w = pack2(e6,e7);
      *(uint4*)&pbs[wv][qi][rbase + lg*4] = pk;
    }
    union { unsigned u[4]; bf16x8 v; } pbv[2];
    #pragma unroll
    for (int qi=0;qi<2;qi++){
      pbv[qi].u[0] = pbs[wv][qi][rbase + lgs01*4 + mi2 + 0];
      pbv[qi].u[1] = pbs[wv][qi][rbase + lgs01*4 + mi2 + 1];
      pbv[qi].u[2] = pbs[wv][qi][rbase + lgs23*4 + mi2 + 0];
      pbv[qi].u[3] = pbs[wv][qi][rbase + lgs23*4 + mi2 + 1];
    }
    // PV: yT(ci, q) += g(ci,m) . P(m,q)
    __builtin_amdgcn_s_setprio(1);
    #pragma unroll
    for (int ct=0;ct<8;ct++){
      acc[0][ct] = MFMA(gf[ct], pbv[0].v, acc[0][ct]);
      acc[1][ct] = MFMA(gf[ct], pbv[1].v, acc[1][ct]);
    }
    __builtin_amdgcn_s_setprio(0);
    if (ms < 48){
      char* D = tiles[cur^1];
      #pragma unroll
      for (int k=0;k<4;k++){ *(uint4*)(D + lw_p[k]) = A[k]; *(uint4*)(D + lw_g[k]) = A[4+k]; }
    }
    __syncthreads();
    cur ^= 1;
  }

  // denominator: lane's q = l16; sum partials across lg groups
  short* ybh = yhi + (size_t)b*NPOS*NCI;
  short* ybl = ylo + (size_t)b*NPOS*NCI;
  #pragma unroll
  for (int qi=0;qi<2;qi++){
    float v = lsum[qi];
    v += __shfl_xor(v, 16); v += __shfl_xor(v, 32);
    float inv = 1.f / v;
    #pragma unroll
    for (int ct=0;ct<8;ct++){
      size_t idx = (size_t)(q0+qi*16+l16)*NCI + ct*16 + lg*4;
      ushort4 h4, l4;
      #pragma unroll
      for (int j=0;j<4;j++){
        float val = acc[qi][ct][j]*inv;
        short hi = f2bf(val);
        ((unsigned short*)&h4)[j] = (unsigned short)hi;
        ((unsigned short*)&l4)[j] = (unsigned short)f2bf(val - bf2f(hi));
      }
      *(ushort4*)&ybh[idx] = h4;
      *(ushort4*)&ybl[idx] = l4;
    }
  }
}

// ---------------- Ww GEMM (hi/lo) + per-channel partials; y read ONCE (cot loop inside) ----------------
// grid (98, 8); block 256; wave = 16 pos; partial slot per wave.
__global__ __launch_bounds__(256) void k_stats(const short* __restrict__ Wwbf, const short* __restrict__ yhi,
                        const short* __restrict__ ylo, const float* __restrict__ bw,
                        float* __restrict__ sum_part, float* __restrict__ sq_part){
  int wv = threadIdx.x>>6, lane = threadIdx.x&63;
  int l16 = lane&15, lg = lane>>4;
  int b = blockIdx.y;
  int p0 = blockIdx.x*64 + wv*16;
  int slot = (b*98 + blockIdx.x)*4 + wv;           // [0,3136)
  const short* ybh = yhi + (size_t)b*NPOS*NCI;
  const short* ybl = ylo + (size_t)b*NPOS*NCI;
  const short* Whi = Wwbf;
  const short* Wlo = Wwbf + 32768;
  bf16x8 bh[4], bl[4];
  #pragma unroll
  for (int ks=0;ks<4;ks++){
    size_t off = (size_t)(p0+l16)*NCI + ks*32 + lg*8;
    bh[ks] = *(const bf16x8*)&ybh[off];
    bl[ks] = *(const bf16x8*)&ybl[off];
  }
  for (int cot=0; cot<16; cot++){
    f32x4 a0 = {};
    #pragma unroll
    for (int ks=0;ks<4;ks++){
      bf16x8 ahi = *(const bf16x8*)&Whi[(cot*16+l16)*NCI + ks*32 + lg*8];
      bf16x8 alo = *(const bf16x8*)&Wlo[(cot*16+l16)*NCI + ks*32 + lg*8];
      a0 = MFMA(ahi, bh[ks], a0);
      a0 = MFMA(ahi, bl[ks], a0);
      a0 = MFMA(alo, bh[ks], a0);
    }
    #pragma unroll
    for (int j=0;j<4;j++){
      int ch = cot*16 + lg*4 + j;
      float v0 = a0[j] + bw[ch];
      float s = v0, q = v0*v0;
      s += __shfl_xor(s,1); s += __shfl_xor(s,2); s += __shfl_xor(s,4); s += __shfl_xor(s,8);
      q += __shfl_xor(q,1); q += __shfl_xor(q,2); q += __shfl_xor(q,4); q += __shfl_xor(q,8);
      if (l16==0){
        sum_part[ch*3136 + slot] = s;
        sq_part [ch*3136 + slot] = q;
      }
    }
  }
}

__global__ void k_finstats(const float* __restrict__ sum_part, const float* __restrict__ sq_part,
                           const float* __restrict__ gamma, const float* __restrict__ beta,
                           float* __restrict__ scale, float* __restrict__ shift){
  __shared__ float r[4][2];
  int c = blockIdx.x;
  int t = threadIdx.x, wv = t>>6;
  float s=0.f, q=0.f;
  for (int k=t; k<3136; k+=256){ s += sum_part[c*3136+k]; q += sq_part[c*3136+k]; }
  #pragma unroll
  for (int off=1; off<64; off<<=1){ s += __shfl_xor(s,off); q += __shfl_xor(q,off); }
  if ((t&63)==0){ r[wv][0]=s; r[wv][1]=q; }
  __syncthreads();
  if (t==0){
    s = r[0][0]+r[1][0]+r[2][0]+r[3][0];
    q = r[0][1]+r[1][1]+r[2][1]+r[3][1];
    float mean = s*(1.f/PTOT);
    float var  = fmaxf(q*(1.f/PTOT) - mean*mean, 0.f);
    float rs = rsqrtf(var + 1e-5f);
    float sc = gamma[c]*rs;
    scale[c]=sc; shift[c]=beta[c]-mean*sc;
  }
}

// ---------------- Ww GEMM (hi/lo) + BN + residual; y read ONCE (cot loop inside) ----------------
__global__ __launch_bounds__(256) void k_out(const short* __restrict__ Wwbf, const short* __restrict__ yhi,
                      const short* __restrict__ ylo, const float* __restrict__ bw,
                      const float* __restrict__ scale, const float* __restrict__ shift,
                      const float* __restrict__ x, float* __restrict__ out){
  int wv = threadIdx.x>>6, lane = threadIdx.x&63;
  int l16 = lane&15, lg = lane>>4;
  int b = blockIdx.y;
  int p0 = blockIdx.x*64 + wv*16;
  const short* ybh = yhi + (size_t)b*NPOS*NCI;
  const short* ybl = ylo + (size_t)b*NPOS*NCI;
  const short* Whi = Wwbf;
  const short* Wlo = Wwbf + 32768;
  bf16x8 bh[4], bl[4];
  #pragma unroll
  for (int ks=0;ks<4;ks++){
    size_t off = (size_t)(p0+l16)*NCI + ks*32 + lg*8;
    bh[ks] = *(const bf16x8*)&ybh[off];
    bl[ks] = *(const bf16x8*)&ybl[off];
  }
  for (int cot=0; cot<16; cot++){
    f32x4 a0 = {};
    #pragma unroll
    for (int ks=0;ks<4;ks++){
      bf16x8 ahi = *(const bf16x8*)&Whi[(cot*16+l16)*NCI + ks*32 + lg*8];
      bf16x8 alo = *(const bf16x8*)&Wlo[(cot*16+l16)*NCI + ks*32 + lg*8];
      a0 = MFMA(ahi, bh[ks], a0);
      a0 = MFMA(ahi, bl[ks], a0);
      a0 = MFMA(alo, bh[ks], a0);
    }
    #pragma unroll
    for (int j=0;j<4;j++){
      int ch = cot*16 + lg*4 + j;
      float bwv = bw[ch], scv = scale[ch], shv = shift[ch];
      size_t idx = ((size_t)b*NC + ch)*NPOS + p0 + l16;
      float v0 = a0[j] + bwv;
      out[idx] = v0*scv + shv + x[idx];
    }
  }
}

extern "C" void kernel_launch(void* const* d_in, const int* in_sizes, int n_in,
                              void* d_out, int out_size, void* d_ws, size_t ws_size,
                              hipStream_t stream){
  const float* x     = (const float*)d_in[0];
  const float* Wg    = (const float*)d_in[1];
  const float* bg    = (const float*)d_in[2];
  const float* Wt    = (const float*)d_in[3];
  const float* bt    = (const float*)d_in[4];
  const float* Wp    = (const float*)d_in[5];
  const float* bp    = (const float*)d_in[6];
  const float* Ww    = (const float*)d_in[7];
  const float* bw    = (const float*)d_in[8];
  const float* gamma = (const float*)d_in[9];
  const float* beta  = (const float*)d_in[10];
  float* out = (float*)d_out;

  char* w = (char*)d_ws;
  short* Wbf   = (short*)w;                       // 163840 el -> 327680 B (Wt,Wp,Wg,Ww_hi,Ww_lo)
  short* xT    = (short*)(w + 327680);            // 25,690,112 B  (reused as y_hi)
  short* theta = (short*)(w + 327680 + 25690112);
  short* phiF  = (short*)((char*)theta + 12845056);   // reused as y_lo
  short* gF    = (short*)((char*)phiF  + 12845056);   // reused for BN partials
  short* phiP  = (short*)((char*)gF    + 12845056);
  short* gP    = (short*)((char*)phiP  + 3211264);
  float* sum_part = (float*)gF;                        // 256*3136*4 = 3,211,264 B
  float* sq_part  = (float*)((char*)gF + 3211264);
  float* scale    = (float*)((char*)gF + 6422528);
  float* shift    = (float*)((char*)gF + 6423552);
  short* yhi = xT;                                // alias: xT dead after k_conv
  short* ylo = phiF;                              // alias: phiF dead after k_pool

  k_cvt_w<<<dim3(512),256,0,stream>>>(Wt,Wp,Wg,Ww,Wbf);
  k_transpose<<<dim3(196,4,8),256,0,stream>>>(x,xT);
  k_conv<<<dim3(49,2,8),256,0,stream>>>(xT,Wbf,bt,bp,bg,theta,phiF,gF);
  k_pool<<<dim3(98,8),256,0,stream>>>(phiF,gF,phiP,gP);
  k_attn<<<dim3(784),128,0,stream>>>(theta,phiP,gP,yhi,ylo);
  const short* Wwbf = Wbf + 98304;
  k_stats<<<dim3(98,8),256,0,stream>>>(Wwbf,yhi,ylo,bw,sum_part,sq_part);
  k_finstats<<<dim3(256),256,0,stream>>>(sum_part,sq_part,gamma,beta,scale,shift);
  k_out<<<dim3(98,8),256,0,stream>>>(Wwbf,yhi,ylo,bw,scale,shift,x,out);
}

// Round 7
// 279.715 us; speedup vs baseline: 1.0957x; 1.0957x over previous
//
#include <hip/hip_runtime.h>
#include <hip/hip_bf16.h>

#define NB 8
#define NC 256
#define NCI 128
#define NPOS 6272   // 8*28*28
#define NM 1568     // 8*14*14
#define PTOT 50176  // 8*6272
#define LOG2E 1.44269504f

typedef __attribute__((ext_vector_type(8))) short bf16x8;
typedef __attribute__((ext_vector_type(4))) float f32x4;
#define MFMA(a,b,c) __builtin_amdgcn_mfma_f32_16x16x32_bf16((a),(b),(c),0,0,0)

__device__ __forceinline__ short f2bf(float f){
  union{float f; unsigned u;} v; v.f=f;
  unsigned r=(v.u + 0x7FFFu + ((v.u>>16)&1u))>>16;
  return (short)r;
}
__device__ __forceinline__ float bf2f(short s){
  union{unsigned u; float f;} v; v.u=((unsigned)(unsigned short)s)<<16; return v.f;
}
__device__ __forceinline__ float exp2v(float x){
  float r; asm("v_exp_f32 %0, %1" : "=v"(r) : "v"(x)); return r;
}
__device__ __forceinline__ unsigned cvtpk(float lo, float hi){
  unsigned r; asm("v_cvt_pk_bf16_f32 %0, %1, %2" : "=v"(r) : "v"(lo), "v"(hi)); return r;
}

// ---------------- weights fp32 -> bf16 (Ww gets hi/lo split) ----------------
__global__ void k_cvt_w(const float* __restrict__ Wt, const float* __restrict__ Wp,
                        const float* __restrict__ Wg, const float* __restrict__ Ww,
                        short* __restrict__ out){
  int i = blockIdx.x*256 + threadIdx.x;   // 131072 total
  if (i < 98304){
    const float* src; int off;
    if (i < 32768)      { src = Wt; off = i; }
    else if (i < 65536) { src = Wp; off = i-32768; }
    else                { src = Wg; off = i-65536; }
    out[i] = f2bf(src[off]);
  } else {
    float v = Ww[i-98304];
    short hi = f2bf(v);
    out[i] = hi;                                  // Ww_hi at [98304,131072)
    out[i+32768] = f2bf(v - bf2f(hi));            // Ww_lo at [131072,163840)
  }
}

// ---------------- x (c,pos) fp32 -> xT (pos,c) bf16 (vectorized b128 stores) ----------------
__global__ void k_transpose(const float* __restrict__ x, short* __restrict__ xT){
  __shared__ float tile[64][33];
  int b = blockIdx.z, c0 = blockIdx.y*64, p0 = blockIdx.x*32;
  int tx = threadIdx.x & 31, ty = threadIdx.x >> 5;   // ty in [0,8)
  const float* xb = x + (size_t)b*NC*NPOS;
  #pragma unroll
  for (int k=0;k<8;k++)
    tile[ty+8*k][tx] = xb[(size_t)(c0+ty+8*k)*NPOS + p0 + tx];
  __syncthreads();
  short* xTb = xT + (size_t)b*NPOS*NC;
  int pos = threadIdx.x >> 3, cg = threadIdx.x & 7;
  bf16x8 v;
  #pragma unroll
  for (int i=0;i<8;i++) v[i] = f2bf(tile[cg*8+i][pos]);
  *(bf16x8*)&xTb[(size_t)(p0+pos)*NC + c0 + cg*8] = v;
}

// ---------------- 3 projection convs fused: one pass over xT, widx loop inside ----------------
// theta (widx 0) is pre-scaled by log2(e) so attention can use raw v_exp_f32 (2^x).
__global__ __launch_bounds__(256) void k_conv(const short* __restrict__ xT, const short* __restrict__ Wbf,
                        const float* __restrict__ bt, const float* __restrict__ bp, const float* __restrict__ bg,
                        short* __restrict__ theta, short* __restrict__ phiF, short* __restrict__ gF){
  int b = blockIdx.z;
  int wv = threadIdx.x >> 6, lane = threadIdx.x & 63;
  int l16 = lane & 15, lg = lane >> 4;
  int p0 = blockIdx.x*128 + wv*32;
  int c0 = blockIdx.y*64;
  const short* xTb = xT + (size_t)b*NPOS*NC;
  bf16x8 a[2][8];
  #pragma unroll
  for (int ps=0;ps<2;ps++)
    #pragma unroll
    for (int ks=0;ks<8;ks++)
      a[ps][ks] = *(const bf16x8*)&xTb[(size_t)(p0+ps*16+l16)*NC + ks*32 + lg*8];
  for (int widx=0; widx<3; widx++){
    const short* Wb = Wbf + widx*32768;
    const float* bias = (widx==0) ? bt : ((widx==1) ? bp : bg);
    short* outp = (widx==0) ? theta : ((widx==1) ? phiF : gF);
    float osc = (widx==0) ? LOG2E : 1.0f;
    float bv[4];
    #pragma unroll
    for (int cs=0;cs<4;cs++) bv[cs] = bias[c0+cs*16+l16];
    f32x4 acc[2][4] = {};
    #pragma unroll
    for (int ks=0;ks<8;ks++)
      #pragma unroll
      for (int cs=0;cs<4;cs++){
        bf16x8 wf = *(const bf16x8*)&Wb[(c0+cs*16+l16)*NC + ks*32 + lg*8];
        acc[0][cs] = MFMA(a[0][ks], wf, acc[0][cs]);
        acc[1][cs] = MFMA(a[1][ks], wf, acc[1][cs]);
      }
    short* ob = outp + (size_t)b*NPOS*NCI;
    #pragma unroll
    for (int ps=0;ps<2;ps++)
      #pragma unroll
      for (int cs=0;cs<4;cs++)
        #pragma unroll
        for (int j=0;j<4;j++){
          int pos = p0 + ps*16 + lg*4 + j;
          int co  = c0 + cs*16 + l16;
          ob[(size_t)pos*NCI + co] = f2bf((acc[ps][cs][j] + bv[cs])*osc);
        }
  }
}

// ---------------- (1,2,2) max-pool: phiF(pos,128)->phiP(M,128); gF(pos,128)->gP(128,M) ----------------
__global__ void k_pool(const short* __restrict__ phiF, const short* __restrict__ gF,
                       short* __restrict__ phiP, short* __restrict__ gP){
  __shared__ short gb[128][17];
  int b = blockIdx.y, m0 = blockIdx.x*16;
  int lm = threadIdx.x >> 4, cg = threadIdx.x & 15, ci0 = cg*8;
  int m = m0 + lm;
  int tt = m/196, r = m%196, h2 = r/14, w2 = r%14;
  int pbase = tt*784 + h2*56 + w2*2;
  const short* pF  = phiF + (size_t)b*NPOS*NCI;
  const short* gFb = gF   + (size_t)b*NPOS*NCI;
  float pb[8], gv[8];
  #pragma unroll
  for (int i=0;i<8;i++){ pb[i]=-1e30f; gv[i]=-1e30f; }
  #pragma unroll
  for (int dh=0;dh<2;dh++)
    #pragma unroll
    for (int dw=0;dw<2;dw++){
      int pos = pbase + dh*28 + dw;
      bf16x8 v = *(const bf16x8*)&pF[(size_t)pos*NCI+ci0];
      bf16x8 g = *(const bf16x8*)&gFb[(size_t)pos*NCI+ci0];
      #pragma unroll
      for (int i=0;i<8;i++){ pb[i]=fmaxf(pb[i],bf2f(v[i])); gv[i]=fmaxf(gv[i],bf2f(g[i])); }
    }
  bf16x8 po;
  #pragma unroll
  for (int i=0;i<8;i++) po[i]=f2bf(pb[i]);
  *(bf16x8*)&phiP[(size_t)b*NM*NCI + (size_t)m*NCI + ci0] = po;
  #pragma unroll
  for (int i=0;i<8;i++) gb[ci0+i][lm] = f2bf(gv[i]);
  __syncthreads();
  if (threadIdx.x < 128){
    int row = threadIdx.x;
    bf16x8 a, c;
    #pragma unroll
    for (int j=0;j<8;j++){ a[j]=gb[row][j]; c[j]=gb[row][8+j]; }
    short* dst = gP + (size_t)b*NCI*NM + (size_t)row*NM + m0;
    *(bf16x8*)&dst[0] = a;
    *(bf16x8*)&dst[8] = c;
  }
}

// ---------------- flash attention v6: phi via LDS dbuf, g direct from L2, exp2+cvt_pk ----------------
__global__ __launch_bounds__(128,2) void k_attn(const short* __restrict__ theta, const short* __restrict__ phiP,
                       const short* __restrict__ gP, short* __restrict__ yhi, short* __restrict__ ylo){
  __shared__ __align__(16) char tiles[2][8192];         // [buf][ phi 32 x 256B ]
  __shared__ __align__(16) unsigned pbs[2][2][320];     // [wave][qi][16 rows x 20 dw]
  int t = threadIdx.x;
  int wv = t >> 6, lane = t & 63;
  int l16 = lane & 15, lg = lane >> 4;
  int b = blockIdx.x & 7, qt = blockIdx.x >> 3;         // batch on low bits -> XCD-local K/V
  int q0 = qt*64 + wv*32;
  const short* th = theta + (size_t)b*NPOS*NCI;
  const char* gph = (const char*)(phiP + (size_t)b*NM*NCI);
  const char* gpg = (const char*)(gP   + (size_t)b*NCI*NM);

  // ---- phi staging: 128 threads stage 8 KB (4 x 16B chunks each) ----
  int pr = (t >> 4) & 7, ps = t & 15;                   // rows pr+8k, slot ps
  int lw_p[4]; size_t go_p[4];
  #pragma unroll
  for (int k=0;k<4;k++){
    lw_p[k] = (pr+8*k)*256 + ((ps ^ pr) << 4);
    go_p[k] = (size_t)(pr+8*k)*256 + ps*16;
  }
  // ---- phi fragment read offsets (swizzled) ----
  int rp[2][4];
  #pragma unroll
  for (int mi=0;mi<2;mi++)
    #pragma unroll
    for (int kc=0;kc<4;kc++)
      rp[mi][kc] = (mi*16+l16)*256 + (((kc*4+lg) ^ (l16 & 7)) << 4);
  // ---- g direct-L2 per-lane base: row ct*16+l16, col chunk lg ----
  const char* gbase = gpg + (size_t)l16*(NM*2) + lg*16;

  // ---- P redistribution constants ----
  int lgs01 = (2*lg) & 3, lgs23 = (2*lg+1) & 3;
  int mi2 = (lg >> 1) * 2;
  int rbase = l16*20;

  // ---- Q fragments (B-operand of swapped QK): rows q0+qi*16+l16 ----
  bf16x8 qf[2][4];
  #pragma unroll
  for (int qi=0;qi<2;qi++)
    #pragma unroll
    for (int kc=0;kc<4;kc++)
      qf[qi][kc] = *(const bf16x8*)&th[(size_t)(q0+qi*16+l16)*NCI + kc*32 + lg*8];
  f32x4 acc[2][8] = {};
  float lsum[2] = {0.f, 0.f};

  // ---- prologue: stage phi tile 0 ----
  {
    uint4 A[4];
    #pragma unroll
    for (int k=0;k<4;k++) A[k] = *(const uint4*)(gph + go_p[k]);
    #pragma unroll
    for (int k=0;k<4;k++) *(uint4*)(tiles[0] + lw_p[k]) = A[k];
  }
  __syncthreads();

  int cur = 0;
  for (int ms=0; ms<49; ms++){
    // next phi tile -> regs (written after compute)
    uint4 A[4];
    if (ms < 48){
      size_t pb_ = (size_t)(ms+1)*8192;
      #pragma unroll
      for (int k=0;k<4;k++) A[k] = *(const uint4*)(gph + pb_ + go_p[k]);
    }
    // current g columns direct from L2 (consumed at PV, ~500cyc later)
    bf16x8 gf[8];
    #pragma unroll
    for (int ct=0;ct<8;ct++)
      gf[ct] = *(const bf16x8*)(gbase + (size_t)ct*16*(NM*2) + (size_t)ms*64);
    const char* L = tiles[cur];
    bf16x8 pf[2][4];
    #pragma unroll
    for (int mi=0;mi<2;mi++)
      #pragma unroll
      for (int kc=0;kc<4;kc++)
        pf[mi][kc] = *(const bf16x8*)(L + rp[mi][kc]);
    // swapped QK: S(row=m, col=q)
    f32x4 s[2][2] = {};
    __builtin_amdgcn_s_setprio(1);
    #pragma unroll
    for (int qi=0;qi<2;qi++)
      #pragma unroll
      for (int mi=0;mi<2;mi++)
        #pragma unroll
        for (int kc=0;kc<4;kc++)
          s[qi][mi] = MFMA(pf[mi][kc], qf[qi][kc], s[qi][mi]);
    __builtin_amdgcn_s_setprio(0);
    // softmax numerators: theta was pre-scaled by log2e -> pure v_exp_f32
    #pragma unroll
    for (int qi=0;qi<2;qi++){
      float e0=exp2v(s[qi][0][0]), e1=exp2v(s[qi][0][1]), e2=exp2v(s[qi][0][2]), e3=exp2v(s[qi][0][3]);
      float e4=exp2v(s[qi][1][0]), e5=exp2v(s[qi][1][1]), e6=exp2v(s[qi][1][2]), e7=exp2v(s[qi][1][3]);
      lsum[qi] += (e0+e1)+(e2+e3)+(e4+e5)+(e6+e7);
      uint4 pk;
      pk.x = cvtpk(e0,e1); pk.y = cvtpk(e2,e3); pk.z = cvtpk(e4,e5); pk.w = cvtpk(e6,e7);
      *(uint4*)&pbs[wv][qi][rbase + lg*4] = pk;
    }
    union { unsigned u[4]; bf16x8 v; } pbv[2];
    #pragma unroll
    for (int qi=0;qi<2;qi++){
      pbv[qi].u[0] = pbs[wv][qi][rbase + lgs01*4 + mi2 + 0];
      pbv[qi].u[1] = pbs[wv][qi][rbase + lgs01*4 + mi2 + 1];
      pbv[qi].u[2] = pbs[wv][qi][rbase + lgs23*4 + mi2 + 0];
      pbv[qi].u[3] = pbs[wv][qi][rbase + lgs23*4 + mi2 + 1];
    }
    // PV: yT(ci, q) += g(ci,m) . P(m,q)
    __builtin_amdgcn_s_setprio(1);
    #pragma unroll
    for (int ct=0;ct<8;ct++){
      acc[0][ct] = MFMA(gf[ct], pbv[0].v, acc[0][ct]);
      acc[1][ct] = MFMA(gf[ct], pbv[1].v, acc[1][ct]);
    }
    __builtin_amdgcn_s_setprio(0);
    if (ms < 48){
      char* D = tiles[cur^1];
      #pragma unroll
      for (int k=0;k<4;k++) *(uint4*)(D + lw_p[k]) = A[k];
    }
    __syncthreads();
    cur ^= 1;
  }

  // denominator: lane's q = l16; sum partials across lg groups
  short* ybh = yhi + (size_t)b*NPOS*NCI;
  short* ybl = ylo + (size_t)b*NPOS*NCI;
  #pragma unroll
  for (int qi=0;qi<2;qi++){
    float v = lsum[qi];
    v += __shfl_xor(v, 16); v += __shfl_xor(v, 32);
    float inv = 1.f / v;
    #pragma unroll
    for (int ct=0;ct<8;ct++){
      size_t idx = (size_t)(q0+qi*16+l16)*NCI + ct*16 + lg*4;
      ushort4 h4, l4;
      #pragma unroll
      for (int j=0;j<4;j++){
        float val = acc[qi][ct][j]*inv;
        short hi = f2bf(val);
        ((unsigned short*)&h4)[j] = (unsigned short)hi;
        ((unsigned short*)&l4)[j] = (unsigned short)f2bf(val - bf2f(hi));
      }
      *(ushort4*)&ybh[idx] = h4;
      *(ushort4*)&ybl[idx] = l4;
    }
  }
}

// ---------------- Ww GEMM (hi/lo) + per-channel partials; y read ONCE (cot loop inside) ----------------
// grid (49, 8); block 256; wave = 32 pos; partial slot per wave.  [round-5 version]
__global__ __launch_bounds__(256) void k_stats(const short* __restrict__ Wwbf, const short* __restrict__ yhi,
                        const short* __restrict__ ylo, const float* __restrict__ bw,
                        float* __restrict__ sum_part, float* __restrict__ sq_part){
  int wv = threadIdx.x>>6, lane = threadIdx.x&63;
  int l16 = lane&15, lg = lane>>4;
  int b = blockIdx.y;
  int p0 = blockIdx.x*128 + wv*32;
  int slot = (b*49 + blockIdx.x)*4 + wv;           // [0,1568)
  const short* ybh = yhi + (size_t)b*NPOS*NCI;
  const short* ybl = ylo + (size_t)b*NPOS*NCI;
  const short* Whi = Wwbf;
  const short* Wlo = Wwbf + 32768;
  bf16x8 bh[2][4], bl[2][4];
  #pragma unroll
  for (int ps=0;ps<2;ps++)
    #pragma unroll
    for (int ks=0;ks<4;ks++){
      size_t off = (size_t)(p0+ps*16+l16)*NCI + ks*32 + lg*8;
      bh[ps][ks] = *(const bf16x8*)&ybh[off];
      bl[ps][ks] = *(const bf16x8*)&ybl[off];
    }
  for (int cot=0; cot<16; cot++){
    bf16x8 ahi[4], alo[4];
    #pragma unroll
    for (int ks=0;ks<4;ks++){
      ahi[ks] = *(const bf16x8*)&Whi[(cot*16+l16)*NCI + ks*32 + lg*8];
      alo[ks] = *(const bf16x8*)&Wlo[(cot*16+l16)*NCI + ks*32 + lg*8];
    }
    f32x4 a0 = {}, a1 = {};
    #pragma unroll
    for (int ks=0;ks<4;ks++){
      a0 = MFMA(ahi[ks], bh[0][ks], a0);
      a0 = MFMA(ahi[ks], bl[0][ks], a0);
      a0 = MFMA(alo[ks], bh[0][ks], a0);
      a1 = MFMA(ahi[ks], bh[1][ks], a1);
      a1 = MFMA(ahi[ks], bl[1][ks], a1);
      a1 = MFMA(alo[ks], bh[1][ks], a1);
    }
    #pragma unroll
    for (int j=0;j<4;j++){
      int ch = cot*16 + lg*4 + j;
      float bwv = bw[ch];
      float v0 = a0[j] + bwv, v1 = a1[j] + bwv;
      float s = v0 + v1, q = v0*v0 + v1*v1;
      s += __shfl_xor(s,1); s += __shfl_xor(s,2); s += __shfl_xor(s,4); s += __shfl_xor(s,8);
      q += __shfl_xor(q,1); q += __shfl_xor(q,2); q += __shfl_xor(q,4); q += __shfl_xor(q,8);
      if (l16==0){
        sum_part[ch*1568 + slot] = s;
        sq_part [ch*1568 + slot] = q;
      }
    }
  }
}

__global__ void k_finstats(const float* __restrict__ sum_part, const float* __restrict__ sq_part,
                           const float* __restrict__ gamma, const float* __restrict__ beta,
                           float* __restrict__ scale, float* __restrict__ shift){
  __shared__ float r[4][2];
  int c = blockIdx.x;
  int t = threadIdx.x, wv = t>>6;
  float s=0.f, q=0.f;
  for (int k=t; k<1568; k+=256){ s += sum_part[c*1568+k]; q += sq_part[c*1568+k]; }
  #pragma unroll
  for (int off=1; off<64; off<<=1){ s += __shfl_xor(s,off); q += __shfl_xor(q,off); }
  if ((t&63)==0){ r[wv][0]=s; r[wv][1]=q; }
  __syncthreads();
  if (t==0){
    s = r[0][0]+r[1][0]+r[2][0]+r[3][0];
    q = r[0][1]+r[1][1]+r[2][1]+r[3][1];
    float mean = s*(1.f/PTOT);
    float var  = fmaxf(q*(1.f/PTOT) - mean*mean, 0.f);
    float rs = rsqrtf(var + 1e-5f);
    float sc = gamma[c]*rs;
    scale[c]=sc; shift[c]=beta[c]-mean*sc;
  }
}

// ---------------- Ww GEMM (hi/lo) + BN + residual; y read ONCE (cot loop inside) [round-5 version] ----------------
__global__ __launch_bounds__(256) void k_out(const short* __restrict__ Wwbf, const short* __restrict__ yhi,
                      const short* __restrict__ ylo, const float* __restrict__ bw,
                      const float* __restrict__ scale, const float* __restrict__ shift,
                      const float* __restrict__ x, float* __restrict__ out){
  int wv = threadIdx.x>>6, lane = threadIdx.x&63;
  int l16 = lane&15, lg = lane>>4;
  int b = blockIdx.y;
  int p0 = blockIdx.x*128 + wv*32;
  const short* ybh = yhi + (size_t)b*NPOS*NCI;
  const short* ybl = ylo + (size_t)b*NPOS*NCI;
  const short* Whi = Wwbf;
  const short* Wlo = Wwbf + 32768;
  bf16x8 bh[2][4], bl[2][4];
  #pragma unroll
  for (int ps=0;ps<2;ps++)
    #pragma unroll
    for (int ks=0;ks<4;ks++){
      size_t off = (size_t)(p0+ps*16+l16)*NCI + ks*32 + lg*8;
      bh[ps][ks] = *(const bf16x8*)&ybh[off];
      bl[ps][ks] = *(const bf16x8*)&ybl[off];
    }
  for (int cot=0; cot<16; cot++){
    bf16x8 ahi[4], alo[4];
    #pragma unroll
    for (int ks=0;ks<4;ks++){
      ahi[ks] = *(const bf16x8*)&Whi[(cot*16+l16)*NCI + ks*32 + lg*8];
      alo[ks] = *(const bf16x8*)&Wlo[(cot*16+l16)*NCI + ks*32 + lg*8];
    }
    f32x4 a0 = {}, a1 = {};
    #pragma unroll
    for (int ks=0;ks<4;ks++){
      a0 = MFMA(ahi[ks], bh[0][ks], a0);
      a0 = MFMA(ahi[ks], bl[0][ks], a0);
      a0 = MFMA(alo[ks], bh[0][ks], a0);
      a1 = MFMA(ahi[ks], bh[1][ks], a1);
      a1 = MFMA(ahi[ks], bl[1][ks], a1);
      a1 = MFMA(alo[ks], bh[1][ks], a1);
    }
    #pragma unroll
    for (int j=0;j<4;j++){
      int ch = cot*16 + lg*4 + j;
      float bwv = bw[ch], scv = scale[ch], shv = shift[ch];
      size_t base = ((size_t)b*NC + ch)*NPOS;
      size_t i0 = base + p0 + l16;
      size_t i1 = base + p0 + 16 + l16;
      float v0 = a0[j] + bwv, v1 = a1[j] + bwv;
      out[i0] = v0*scv + shv + x[i0];
      out[i1] = v1*scv + shv + x[i1];
    }
  }
}

extern "C" void kernel_launch(void* const* d_in, const int* in_sizes, int n_in,
                              void* d_out, int out_size, void* d_ws, size_t ws_size,
                              hipStream_t stream){
  const float* x     = (const float*)d_in[0];
  const float* Wg    = (const float*)d_in[1];
  const float* bg    = (const float*)d_in[2];
  const float* Wt    = (const float*)d_in[3];
  const float* bt    = (const float*)d_in[4];
  const float* Wp    = (const float*)d_in[5];
  const float* bp    = (const float*)d_in[6];
  const float* Ww    = (const float*)d_in[7];
  const float* bw    = (const float*)d_in[8];
  const float* gamma = (const float*)d_in[9];
  const float* beta  = (const float*)d_in[10];
  float* out = (float*)d_out;

  char* w = (char*)d_ws;
  short* Wbf   = (short*)w;                       // 163840 el -> 327680 B (Wt,Wp,Wg,Ww_hi,Ww_lo)
  short* xT    = (short*)(w + 327680);            // 25,690,112 B  (reused as y_hi)
  short* theta = (short*)(w + 327680 + 25690112);
  short* phiF  = (short*)((char*)theta + 12845056);   // reused as y_lo
  short* gF    = (short*)((char*)phiF  + 12845056);   // reused for BN partials
  short* phiP  = (short*)((char*)gF    + 12845056);
  short* gP    = (short*)((char*)phiP  + 3211264);
  float* sum_part = (float*)gF;                        // 256*1568*4 = 1,605,632 B
  float* sq_part  = (float*)((char*)gF + 1605632);
  float* scale    = (float*)((char*)gF + 3211264);
  float* shift    = (float*)((char*)gF + 3212288);
  short* yhi = xT;                                // alias: xT dead after k_conv
  short* ylo = phiF;                              // alias: phiF dead after k_pool

  k_cvt_w<<<dim3(512),256,0,stream>>>(Wt,Wp,Wg,Ww,Wbf);
  k_transpose<<<dim3(196,4,8),256,0,stream>>>(x,xT);
  k_conv<<<dim3(49,2,8),256,0,stream>>>(xT,Wbf,bt,bp,bg,theta,phiF,gF);
  k_pool<<<dim3(98,8),256,0,stream>>>(phiF,gF,phiP,gP);
  k_attn<<<dim3(784),128,0,stream>>>(theta,phiP,gP,yhi,ylo);
  const short* Wwbf = Wbf + 98304;
  k_stats<<<dim3(49,8),256,0,stream>>>(Wwbf,yhi,ylo,bw,sum_part,sq_part);
  k_finstats<<<dim3(256),256,0,stream>>>(sum_part,sq_part,gamma,beta,scale,shift);
  k_out<<<dim3(49,8),256,0,stream>>>(Wwbf,yhi,ylo,bw,scale,shift,x,out);
}